// Round 1
// baseline (310.257 us; speedup 1.0000x reference)
//
#include <hip/hip_runtime.h>
#include <stdint.h>

#define TS 2048
#define DM 2048
#define NH 16
#define DH 128

typedef unsigned short u16t;
typedef __attribute__((ext_vector_type(8))) short short8;
typedef __attribute__((ext_vector_type(4))) float f32x4;
typedef __attribute__((ext_vector_type(4))) unsigned int u32x4;

__device__ __forceinline__ float bf2f(u16t b) {
  return __uint_as_float(((unsigned int)b) << 16);
}
__device__ __forceinline__ u16t f2bf(float f) {
  unsigned int u = __float_as_uint(f);
  u += 0x7FFFu + ((u >> 16) & 1u);   // round-to-nearest-even
  return (u16t)(u >> 16);
}

// async global->LDS, 16B per lane. LDS dest = wave-uniform base + lane*16.
__device__ __forceinline__ void async_copy16(const u16t* g, u16t* l) {
  __builtin_amdgcn_global_load_lds((const __attribute__((address_space(1))) void*)g,
                                   (__attribute__((address_space(3))) void*)l, 16, 0, 0);
}

// DPP row_ror within 16-lane rows: pure-VALU cross-lane (vs ds_bpermute for __shfl).
#define DPP_ROR_F(x, n) __uint_as_float(__builtin_amdgcn_update_dpp( \
    0, (int)__float_as_uint(x), 0x120 | (n), 0xF, 0xF, true))

__device__ __forceinline__ float row16_max(float x) {
  x = fmaxf(x, DPP_ROR_F(x, 8));
  x = fmaxf(x, DPP_ROR_F(x, 4));
  x = fmaxf(x, DPP_ROR_F(x, 2));
  x = fmaxf(x, DPP_ROR_F(x, 1));
  return x;
}
__device__ __forceinline__ float row16_sum(float x) {
  x += DPP_ROR_F(x, 8);
  x += DPP_ROR_F(x, 4);
  x += DPP_ROR_F(x, 2);
  x += DPP_ROR_F(x, 1);
  return x;
}

// ---------------- fused: fp32->bf16 weight cast (blocks 0..16383) + RMSNorm (rest) ----
// Wq/Wk rows are PERMUTED within each head at cast time so that RoPE partners
// (d, d+64) land at columns (p, p+16): p = (d>>4)*32 + (d&15) [+16 for d>=64].
// In the GEMM C-fragment, col and col+16 are the same lane / adjacent nt register,
// so RoPE becomes a pure in-register epilogue op. Q.K dot is invariant (same perm).
__global__ __launch_bounds__(256) void cast_rms_kernel(const float* __restrict__ W0,
                                                       const float* __restrict__ W1,
                                                       const float* __restrict__ W2,
                                                       const float* __restrict__ W3,
                                                       u16t* __restrict__ outw,
                                                       const float* __restrict__ x,
                                                       const float* __restrict__ lnw,
                                                       u16t* __restrict__ h) {
  if (blockIdx.x < 16384) {
    const int idx = blockIdx.x * 256 + threadIdx.x;   // 4M threads, 4 elems each
    const int mat = idx >> 20;
    const size_t off = (size_t)(idx & 0xFFFFF) * 4;
    const float* W = (mat == 0) ? W0 : (mat == 1) ? W1 : (mat == 2) ? W2 : W3;
    const f32x4 v = *(const f32x4*)(W + off);
    size_t dstoff = off;
    if (mat < 2) {   // permute output-feature rows of Wq, Wk
      const int row = (int)(off >> 11);
      const int col = (int)(off & 2047);
      const int d = row & 127;
      const int e = d & 63;
      const int p = ((e >> 4) * 32 + (e & 15)) + ((d >> 6) << 4);
      dstoff = ((size_t)((row & ~127) | p) << 11) | (size_t)col;
    }
    union { u16t s[4]; uint64_t u; } o;
#pragma unroll
    for (int i = 0; i < 4; ++i) o.s[i] = f2bf(v[i]);
    *(uint64_t*)(outw + (size_t)mat * (DM * DM) + dstoff) = o.u;
    return;
  }
  const int row = blockIdx.x - 16384;
  const int tid = threadIdx.x;
  const float* xr = x + (size_t)row * DM + tid * 8;
  f32x4 v0 = *(const f32x4*)(xr);
  f32x4 v1 = *(const f32x4*)(xr + 4);
  float f[8];
#pragma unroll
  for (int i = 0; i < 4; ++i) { f[i] = v0[i]; f[i + 4] = v1[i]; }
  float ss = 0.f;
#pragma unroll
  for (int i = 0; i < 8; ++i) ss += f[i] * f[i];
#pragma unroll
  for (int off = 1; off < 64; off <<= 1) ss += __shfl_xor(ss, off, 64);
  __shared__ float wsum[4];
  if ((tid & 63) == 0) wsum[tid >> 6] = ss;
  __syncthreads();
  float tot = wsum[0] + wsum[1] + wsum[2] + wsum[3];
  float rs = rsqrtf(tot * (1.0f / DM) + 1e-5f);
  f32x4 w0 = *(const f32x4*)(lnw + tid * 8);
  f32x4 w1 = *(const f32x4*)(lnw + tid * 8 + 4);
  u32x4 o;
#pragma unroll
  for (int i = 0; i < 4; ++i) {
    unsigned int lo = f2bf(f[2 * i]     * ((2 * i     < 4) ? w0[2 * i]     : w1[2 * i - 4]) * rs);
    unsigned int hi = f2bf(f[2 * i + 1] * ((2 * i + 1 < 4) ? w0[2 * i + 1] : w1[2 * i - 3]) * rs);
    o[i] = lo | (hi << 16);
  }
  *(u32x4*)(h + (size_t)row * DM + tid * 8) = o;
}

// ---------------- GEMM C = A * B^T (bf16 A,B row-major, K contiguous) ----------------
// 128x128 tile, BK=32, 4 waves each 64x64. Full-K (no split-K): fp32 accumulation,
// single bf16 rounding, and fused epilogues eliminate both combine kernels.
// MODE 0: z = mat. mat 0/1 -> Q/K with fused in-register RoPE (weights pre-permuted
//         in cast_rms so pairs are (nt, nt+1)); mat 2 -> Vt transposed store.
// MODE 1: out-proj; epilogue fuses out = x + mask_row * acc, fp32 store to d_out.
template <int MODE>
__global__ __launch_bounds__(256) void gemm_bt(
    const u16t* __restrict__ A,
    const u16t* __restrict__ B0, const u16t* __restrict__ B1, const u16t* __restrict__ B2,
    u16t* __restrict__ Cq, u16t* __restrict__ Ck, u16t* __restrict__ Cv,
    const float* __restrict__ cosb, const float* __restrict__ sinb,
    const float* __restrict__ xres, const int* __restrict__ am, float* __restrict__ out) {
  __shared__ u16t Alds[128 * 32];
  __shared__ u16t Blds[128 * 32];
  const int tid  = threadIdx.x;
  const int wave = tid >> 6;
  const int lane = tid & 63;
  const int lin  = blockIdx.y * 16 + blockIdx.x;
  const int xcd  = lin & 7;
  const int sidx = lin >> 3;
  const int m0 = (sidx & 15) * 128;
  const int n0 = ((xcd << 1) | (sidx >> 4)) * 128;
  const int mat = (MODE == 0) ? blockIdx.z : 0;
  const u16t* B = (MODE == 0) ? (mat == 0 ? B0 : (mat == 1 ? B1 : B2)) : B0;

  const f32x4 fzero = {0.f, 0.f, 0.f, 0.f};
  f32x4 acc[4][4];
#pragma unroll
  for (int i = 0; i < 4; ++i)
#pragma unroll
    for (int j = 0; j < 4; ++j) acc[i][j] = fzero;

  const int lr = lane >> 2;   // 0..15 row within 16-row chunk
  const int lc = lane & 3;    // 0..3  8-elem column chunk
  const int mw = (wave >> 1) * 64;
  const int nw = (wave & 1) * 64;
  const int quad = lane >> 4;
  const int c16  = lane & 15;

  for (int k0 = 0; k0 < DM; k0 += 32) {
    __syncthreads();
#pragma unroll
    for (int c = 0; c < 2; ++c) {
      const int ch = wave * 2 + c;        // 8 chunks of 1KB each per tile
      const int r  = ch * 16 + lr;
      async_copy16(A + (size_t)(m0 + r) * DM + k0 + lc * 8, Alds + ch * 512);
      async_copy16(B + (size_t)(n0 + r) * DM + k0 + lc * 8, Blds + ch * 512);
    }
    __syncthreads();
    short8 af[4], bfr[4];
#pragma unroll
    for (int mt = 0; mt < 4; ++mt)
      af[mt] = *(const short8*)(Alds + (mw + mt * 16 + c16) * 32 + quad * 8);
#pragma unroll
    for (int nt = 0; nt < 4; ++nt)
      bfr[nt] = *(const short8*)(Blds + (nw + nt * 16 + c16) * 32 + quad * 8);
#pragma unroll
    for (int mt = 0; mt < 4; ++mt)
#pragma unroll
      for (int nt = 0; nt < 4; ++nt)
        acc[mt][nt] = __builtin_amdgcn_mfma_f32_16x16x32_bf16(af[mt], bfr[nt], acc[mt][nt], 0, 0, 0);
  }

  if (MODE == 1) {
    // fused residual + row-mask epilogue, fp32 store direct to output
#pragma unroll
    for (int mt = 0; mt < 4; ++mt) {
#pragma unroll
      for (int r = 0; r < 4; ++r) {
        const int row = m0 + mw + mt * 16 + quad * 4 + r;
        const float mk = (am[row] != 0) ? 1.f : 0.f;
        const size_t base = (size_t)row * DM;
#pragma unroll
        for (int nt = 0; nt < 4; ++nt) {
          const int col = n0 + nw + nt * 16 + c16;
          out[base + col] = xres[base + col] + mk * acc[mt][nt][r];
        }
      }
    }
    return;
  }

  if (mat == 2) {   // Vt: transposed store
#pragma unroll
    for (int mt = 0; mt < 4; ++mt) {
#pragma unroll
      for (int r = 0; r < 4; ++r) {
        const int row = m0 + mw + mt * 16 + quad * 4 + r;
#pragma unroll
        for (int nt = 0; nt < 4; ++nt) {
          const int col = n0 + nw + nt * 16 + c16;
          Cv[(size_t)col * TS + row] = f2bf(acc[mt][nt][r]);
        }
      }
    }
    return;
  }

  // Q/K with fused RoPE. Weights row-permuted: partner of col is col+16,
  // i.e. acc[mt][nt] pairs with acc[mt][nt+1] (nt even). For position p = col&127
  // (bit4 == 0 here): original d = (p>>5)*16 + (p&15), in [0,64).
  u16t* C = mat ? Ck : Cq;
#pragma unroll
  for (int mt = 0; mt < 4; ++mt) {
#pragma unroll
    for (int r = 0; r < 4; ++r) {
      const int row = m0 + mw + mt * 16 + quad * 4 + r;   // = t
      const size_t base = (size_t)row * DM;
#pragma unroll
      for (int ntp = 0; ntp < 4; ntp += 2) {
        const int col = n0 + nw + ntp * 16 + c16;
        const int p = col & 127;
        const int dorig = (p >> 5) * 16 + c16;
        const float cv = cosb[row * DH + dorig];
        const float sv = sinb[row * DH + dorig];
        const float x1 = acc[mt][ntp][r];
        const float x2 = acc[mt][ntp + 1][r];
        C[base + col]      = f2bf(x1 * cv - x2 * sv);
        C[base + col + 16] = f2bf(x2 * cv + x1 * sv);
      }
    }
  }
}

// ---------------- Flash attention (causal), LDS-staged K/V, 128-key tiles ----------------
__global__ __launch_bounds__(256) void attn_kernel(const u16t* __restrict__ Q,
                                                   const u16t* __restrict__ K,
                                                   const u16t* __restrict__ Vt,
                                                   const int* __restrict__ am,
                                                   u16t* __restrict__ O) {
  __shared__ u16t Klds[128 * 128];   // [key][d], swizzled granules, 32 KB
  __shared__ u16t Vlds[128 * 128];   // [d][key], swizzled granules, 32 KB
  __shared__ u16t Plds[4][2048];     // per-wave P: 4 chunks of 16x32, 16 KB
  const int wave = threadIdx.x >> 6;
  const int lane = threadIdx.x & 63;
  const int x    = blockIdx.x;
  const int half = x >> 8;                  // 0: qt 31..16, 1: qt 0..15
  const int idx  = x & 255;
  const int head = idx & (NH - 1);
  const int grp  = idx >> 4;                // 0..15
  const int qt   = half ? grp : (TS / 64 - 1 - grp);
  const int q0   = qt * 64 + wave * 16;
  const int quad = lane >> 4;
  const int c16  = lane & 15;
  const u16t* Qh  = Q + head * DH;
  const u16t* Kh  = K + head * DH;
  const u16t* Vth = Vt + (size_t)head * DH * TS;
  u16t* Pw = Plds[wave];

  const int row_s = (lane >> 4);    // 0..3 row within chunk
  const int g_s   = (lane & 15);    // granule slot

  short8 qf[4];
#pragma unroll
  for (int dc = 0; dc < 4; ++dc)
    qf[dc] = *(const short8*)(Qh + (size_t)(q0 + c16) * DM + dc * 32 + quad * 8);

  const f32x4 fzero = {0.f, 0.f, 0.f, 0.f};
  float m_run[4], l_run[4];
  f32x4 o_acc[8];
#pragma unroll
  for (int r = 0; r < 4; ++r) { m_run[r] = -1e30f; l_run[r] = 0.f; }
#pragma unroll
  for (int nt = 0; nt < 8; ++nt) o_acc[nt] = fzero;

  const float scale = 0.08838834764831845f;  // 1/sqrt(128)
  const int ntiles = (qt * 64 + 191) >> 7;   // 128-wide tiles covering keys 0..q0+63

  for (int kt = 0; kt < ntiles; ++kt) {
    const int k0 = kt * 128;
    __syncthreads();
#pragma unroll
    for (int c = 0; c < 8; ++c) {
      const int ch = wave * 8 + c;
      const int r  = 4 * ch + row_s;           // 0..127
      const int g  = g_s ^ (r & 15);
      async_copy16(Kh + (size_t)(k0 + r) * DM + g * 8, Klds + ch * 512);
      async_copy16(Vth + (size_t)r * TS + k0 + g * 8, Vlds + ch * 512);
    }
    __syncthreads();

    f32x4 s[8];
#pragma unroll
    for (int ns = 0; ns < 8; ++ns) {
      f32x4 sa = fzero;
      const int rr = ns * 16 + c16;
#pragma unroll
      for (int dc = 0; dc < 4; ++dc) {
        short8 kf = *(const short8*)(Klds + rr * 128 + (((dc * 4 + quad) ^ c16) * 8));
        sa = __builtin_amdgcn_mfma_f32_16x16x32_bf16(qf[dc], kf, sa, 0, 0, 0);
      }
      s[ns] = sa;
    }

    float pv[8][4], tmax[4];
#pragma unroll
    for (int r = 0; r < 4; ++r) tmax[r] = -1e30f;
#pragma unroll
    for (int ns = 0; ns < 8; ++ns) {
      const int key = k0 + ns * 16 + c16;
      const bool kok = (am[key] != 0);
#pragma unroll
      for (int r = 0; r < 4; ++r) {
        const int qrow = q0 + quad * 4 + r;
        float v = s[ns][r] * scale;
        if (key > qrow || !kok) v = -1e30f;
        pv[ns][r] = v;
        tmax[r] = fmaxf(tmax[r], v);
      }
    }
    float alpha[4], rsum[4];
#pragma unroll
    for (int r = 0; r < 4; ++r) {
      const float mn = fmaxf(m_run[r], row16_max(tmax[r]));
      alpha[r] = __expf(m_run[r] - mn);
      m_run[r] = mn;
      float rs = 0.f;
#pragma unroll
      for (int ns = 0; ns < 8; ++ns) {
        const float e = __expf(pv[ns][r] - mn);
        pv[ns][r] = e;
        rs += e;
      }
      rsum[r] = row16_sum(rs);
      l_run[r] = l_run[r] * alpha[r] + rsum[r];
    }

#pragma unroll
    for (int ns = 0; ns < 8; ++ns)
#pragma unroll
      for (int r = 0; r < 4; ++r)
        Pw[(ns >> 1) * 512 + (quad * 4 + r) * 32 + (ns & 1) * 16 + c16] = f2bf(pv[ns][r]);
    asm volatile("s_waitcnt lgkmcnt(0)" ::: "memory");
    short8 pf[4];
#pragma unroll
    for (int c = 0; c < 4; ++c)
      pf[c] = *(const short8*)(Pw + c * 512 + c16 * 32 + quad * 8);

#pragma unroll
    for (int nt = 0; nt < 8; ++nt)
#pragma unroll
      for (int r = 0; r < 4; ++r) o_acc[nt][r] *= alpha[r];
#pragma unroll
    for (int nt = 0; nt < 8; ++nt) {
      const int rr = nt * 16 + c16;
#pragma unroll
      for (int c = 0; c < 4; ++c) {
        short8 vf = *(const short8*)(Vlds + rr * 128 + (((c * 4 + quad) ^ c16) * 8));
        o_acc[nt] = __builtin_amdgcn_mfma_f32_16x16x32_bf16(pf[c], vf, o_acc[nt], 0, 0, 0);
      }
    }
  }

#pragma unroll
  for (int r = 0; r < 4; ++r) {
    const float inv = 1.0f / fmaxf(l_run[r], 1e-20f);
    const int qrow = q0 + quad * 4 + r;
#pragma unroll
    for (int nt = 0; nt < 8; ++nt)
      O[(size_t)qrow * DM + head * DH + nt * 16 + c16] = f2bf(o_acc[nt][r] * inv);
  }
}

extern "C" void kernel_launch(void* const* d_in, const int* in_sizes, int n_in,
                              void* d_out, int out_size, void* d_ws, size_t ws_size,
                              hipStream_t stream) {
  const float* x    = (const float*)d_in[0];
  const float* cosb = (const float*)d_in[1];
  const float* sinb = (const float*)d_in[2];
  const int*   am   = (const int*)d_in[3];
  const float* lnw  = (const float*)d_in[4];
  const float* Wq   = (const float*)d_in[5];
  const float* Wk   = (const float*)d_in[6];
  const float* Wv   = (const float*)d_in[7];
  const float* Wo   = (const float*)d_in[8];
  float* out = (float*)d_out;

  u16t* h    = (u16t*)d_ws;                 // (T, D) bf16   [0, 8 MB)
  u16t* Q    = h + (size_t)TS * DM;         //               [8, 16)
  u16t* K    = Q + (size_t)TS * DM;         //               [16, 24)
  u16t* Vt   = K + (size_t)TS * DM;         //               [24, 32)
  u16t* attn = Vt + (size_t)TS * DM;        //               [32, 40)
  u16t* Wb   = attn + (size_t)TS * DM;      // 4 x (D, D)    [40, 72)
  u16t* Wqb = Wb;
  u16t* Wkb = Wb + (size_t)DM * DM;
  u16t* Wvb = Wb + 2 * (size_t)DM * DM;
  u16t* Wob = Wb + 3 * (size_t)DM * DM;

  cast_rms_kernel<<<16384 + TS, 256, 0, stream>>>(Wq, Wk, Wv, Wo, Wb, x, lnw, h);
  // QKV full-K (768 blocks, ~3/CU), RoPE fused in epilogue, Vt stored transposed
  gemm_bt<0><<<dim3(16, 16, 3), 256, 0, stream>>>(h, Wqb, Wkb, Wvb, Q, K, Vt,
                                                  cosb, sinb, nullptr, nullptr, nullptr);
  attn_kernel<<<NH * (TS / 64), 256, 0, stream>>>(Q, K, Vt, am, attn);
  // out-proj full-K, fused residual+mask epilogue, fp32 store direct to out
  gemm_bt<1><<<dim3(16, 16, 1), 256, 0, stream>>>(attn, Wob, nullptr, nullptr,
                                                  nullptr, nullptr, nullptr,
                                                  nullptr, nullptr, x, am, out);
}

// Round 4
// 299.835 us; speedup vs baseline: 1.0348x; 1.0348x over previous
//
#include <hip/hip_runtime.h>
#include <stdint.h>

#define TS 2048
#define DM 2048
#define NH 16
#define DH 128

typedef unsigned short u16t;
typedef __attribute__((ext_vector_type(8))) short short8;
typedef __attribute__((ext_vector_type(4))) float f32x4;
typedef __attribute__((ext_vector_type(4))) unsigned int u32x4;
typedef __attribute__((ext_vector_type(4))) unsigned short u16x4;

__device__ __forceinline__ float bf2f(u16t b) {
  return __uint_as_float(((unsigned int)b) << 16);
}
__device__ __forceinline__ u16t f2bf(float f) {
  unsigned int u = __float_as_uint(f);
  u += 0x7FFFu + ((u >> 16) & 1u);   // round-to-nearest-even
  return (u16t)(u >> 16);
}

// async global->LDS, 16B per lane. LDS dest = wave-uniform base + lane*16.
__device__ __forceinline__ void async_copy16(const u16t* g, u16t* l) {
  __builtin_amdgcn_global_load_lds((const __attribute__((address_space(1))) void*)g,
                                   (__attribute__((address_space(3))) void*)l, 16, 0, 0);
}

// DPP row_ror within 16-lane rows: pure-VALU cross-lane (vs ds_bpermute for __shfl).
#define DPP_ROR_F(x, n) __uint_as_float(__builtin_amdgcn_update_dpp( \
    0, (int)__float_as_uint(x), 0x120 | (n), 0xF, 0xF, true))

__device__ __forceinline__ float row16_max(float x) {
  x = fmaxf(x, DPP_ROR_F(x, 8));
  x = fmaxf(x, DPP_ROR_F(x, 4));
  x = fmaxf(x, DPP_ROR_F(x, 2));
  x = fmaxf(x, DPP_ROR_F(x, 1));
  return x;
}
__device__ __forceinline__ float row16_sum(float x) {
  x += DPP_ROR_F(x, 8);
  x += DPP_ROR_F(x, 4);
  x += DPP_ROR_F(x, 2);
  x += DPP_ROR_F(x, 1);
  return x;
}

// ---------------- fused: fp32->bf16 weight cast (blocks 0..16383) + RMSNorm (rest) ----
// Wq/Wk rows are PERMUTED within each head at cast time so that RoPE partners
// (d, d+64) land at columns (p, p+16): p = (d>>4)*32 + (d&15) [+16 for d>=64].
// In the GEMM C-fragment, col and col+16 are the same lane / adjacent nt register,
// so RoPE becomes a pure in-register epilogue op. Q.K dot is invariant (same perm).
__global__ __launch_bounds__(256) void cast_rms_kernel(const float* __restrict__ W0,
                                                       const float* __restrict__ W1,
                                                       const float* __restrict__ W2,
                                                       const float* __restrict__ W3,
                                                       u16t* __restrict__ outw,
                                                       const float* __restrict__ x,
                                                       const float* __restrict__ lnw,
                                                       u16t* __restrict__ h) {
  if (blockIdx.x < 16384) {
    const int idx = blockIdx.x * 256 + threadIdx.x;   // 4M threads, 4 elems each
    const int mat = idx >> 20;
    const size_t off = (size_t)(idx & 0xFFFFF) * 4;
    const float* W = (mat == 0) ? W0 : (mat == 1) ? W1 : (mat == 2) ? W2 : W3;
    const f32x4 v = *(const f32x4*)(W + off);
    size_t dstoff = off;
    if (mat < 2) {   // permute output-feature rows of Wq, Wk
      const int row = (int)(off >> 11);
      const int col = (int)(off & 2047);
      const int d = row & 127;
      const int e = d & 63;
      const int p = ((e >> 4) * 32 + (e & 15)) + ((d >> 6) << 4);
      dstoff = ((size_t)((row & ~127) | p) << 11) | (size_t)col;
    }
    union { u16t s[4]; uint64_t u; } o;
#pragma unroll
    for (int i = 0; i < 4; ++i) o.s[i] = f2bf(v[i]);
    *(uint64_t*)(outw + (size_t)mat * (DM * DM) + dstoff) = o.u;
    return;
  }
  const int row = blockIdx.x - 16384;
  const int tid = threadIdx.x;
  const float* xr = x + (size_t)row * DM + tid * 8;
  f32x4 v0 = *(const f32x4*)(xr);
  f32x4 v1 = *(const f32x4*)(xr + 4);
  float f[8];
#pragma unroll
  for (int i = 0; i < 4; ++i) { f[i] = v0[i]; f[i + 4] = v1[i]; }
  float ss = 0.f;
#pragma unroll
  for (int i = 0; i < 8; ++i) ss += f[i] * f[i];
#pragma unroll
  for (int off = 1; off < 64; off <<= 1) ss += __shfl_xor(ss, off, 64);
  __shared__ float wsum[4];
  if ((tid & 63) == 0) wsum[tid >> 6] = ss;
  __syncthreads();
  float tot = wsum[0] + wsum[1] + wsum[2] + wsum[3];
  float rs = rsqrtf(tot * (1.0f / DM) + 1e-5f);
  f32x4 w0 = *(const f32x4*)(lnw + tid * 8);
  f32x4 w1 = *(const f32x4*)(lnw + tid * 8 + 4);
  u32x4 o;
#pragma unroll
  for (int i = 0; i < 4; ++i) {
    unsigned int lo = f2bf(f[2 * i]     * ((2 * i     < 4) ? w0[2 * i]     : w1[2 * i - 4]) * rs);
    unsigned int hi = f2bf(f[2 * i + 1] * ((2 * i + 1 < 4) ? w0[2 * i + 1] : w1[2 * i - 3]) * rs);
    o[i] = lo | (hi << 16);
  }
  *(u32x4*)(h + (size_t)row * DM + tid * 8) = o;
}

// ---------------- 256x256 8-phase GEMM C = A * B^T (bf16, K contiguous) ----------------
// T2+T3+T4+T5 per the verified 8-phase template: BK=64, 8 waves (2M x 4N), 128 KiB
// double-buffered LDS, per-phase {ds_read subtile; barrier; lgkmcnt(0); setprio(1);
// 16 MFMA; setprio(0); barrier}; COUNTED vmcnt(8) at iteration top (vmcnt(0) only at
// the last tile); stage of tile kt+2 issued at iteration end into the buffer just
// freed. LDS swizzle: 16B granule g XOR (row&7), applied BOTH sides: pre-swizzled
// global source for global_load_lds (linear LDS dest) + XOR'd ds_read address.
// MODE 0: blocks = 8m x 8n x 3 mats. mat 0/1 -> Q/K fused in-register RoPE
//         (weights pre-permuted); mat 2 -> Vt transposed store.
// MODE 1: out-proj split-K=4 (mat = wgid>>6), bf16 partial store to P0..P3.
template <int MODE>
__global__ __launch_bounds__(512, 2) void gemm8(
    const u16t* __restrict__ A,
    const u16t* __restrict__ B0, const u16t* __restrict__ B1, const u16t* __restrict__ B2,
    u16t* __restrict__ Cq, u16t* __restrict__ Ck, u16t* __restrict__ Cv,
    u16t* __restrict__ P0, u16t* __restrict__ P1,
    u16t* __restrict__ P2, u16t* __restrict__ P3,
    const float* __restrict__ cosb, const float* __restrict__ sinb) {
  __shared__ u16t Ab[2][256 * 64];   // 64 KB (2 x 32 KB)
  __shared__ u16t Bb[2][256 * 64];   // 64 KB
  const int tid  = threadIdx.x;
  const int wave = tid >> 6;
  const int lane = tid & 63;
  const int quad = lane >> 4;
  const int c16  = lane & 15;
  const int h7   = c16 & 7;
  const int wm   = wave >> 2;        // 0..1  (M half)
  const int wn   = wave & 3;         // 0..3  (N quarter)
  // XCD-aware swizzle (grid % 8 == 0 in both modes -> bijective)
  const int nwg  = gridDim.x;
  const int bid  = blockIdx.x;
  const int wgid = (bid & 7) * (nwg >> 3) + (bid >> 3);
  const int mat  = wgid >> 6;        // MODE0: matrix 0..2, MODE1: K-slice 0..3
  const int rem  = wgid & 63;
  const int m0   = (rem & 7) * 256;
  const int n0   = ((rem >> 3) & 7) * 256;
  const u16t* B  = (MODE == 0) ? (mat == 0 ? B0 : (mat == 1 ? B1 : B2)) : B0;
  const int kbeg = (MODE == 0) ? 0 : mat * (DM / 4);
  const int NT   = (MODE == 0) ? (DM / 64) : (DM / 4 / 64);   // 32 or 8 K-tiles

  // staging: per wave 8 x global_load_lds per K-tile (4 A-chunks + 4 B-chunks,
  // chunk = 8 rows x 128B = 1KB). lane -> row srow, granule (lane&7)^srow so that
  // LDS[r][j] holds global granule j^(r&7)  (involution; read applies same XOR).
  const int srow = lane >> 3;               // 0..7
  const int sg   = (lane & 7) ^ srow;       // permuted 16B granule
  auto stage = [&](int d, int k0) {
    const size_t koff = (size_t)k0 + sg * 8;
#pragma unroll
    for (int c = 0; c < 4; ++c) {
      const int rb = wave * 32 + c * 8;     // chunk row base (multiple of 8)
      async_copy16(A + (size_t)(m0 + rb + srow) * DM + koff, &Ab[d][rb * 64]);
      async_copy16(B + (size_t)(n0 + rb + srow) * DM + koff, &Bb[d][rb * 64]);
    }
  };

  const f32x4 fzero = {0.f, 0.f, 0.f, 0.f};
  f32x4 acc[8][4];
#pragma unroll
  for (int i = 0; i < 8; ++i)
#pragma unroll
    for (int j = 0; j < 4; ++j) acc[i][j] = fzero;

  // prologue: tiles 0 and 1
  stage(0, kbeg);
  stage(1, kbeg + 64);

  for (int kt = 0; kt < NT; ++kt) {
    const int cur = kt & 1;
    // T4: counted wait — tile kt's 8 loads are the oldest; tile kt+1's stay in flight.
    if (kt < NT - 1) { asm volatile("s_waitcnt vmcnt(8)" ::: "memory"); }
    else             { asm volatile("s_waitcnt vmcnt(0)" ::: "memory"); }
    __builtin_amdgcn_s_barrier();
    const u16t* Abuf = Ab[cur];
    const u16t* Bbuf = Bb[cur];
    short8 bf[4];
#pragma unroll
    for (int ph = 0; ph < 4; ++ph) {         // 4 phases per K-tile
      const int hh = ph & 1;                 // M-half of this wave's 8 frags
      const int ks = ph >> 1;                // K sub-step (0: k 0..31, 1: k 32..63)
      short8 af[4];
#pragma unroll
      for (int i = 0; i < 4; ++i) {
        const int row = wm * 128 + (hh * 4 + i) * 16 + c16;
        af[i] = *(const short8*)(Abuf + row * 64 + (((ks * 4 + quad) ^ h7) * 8));
      }
      if (hh == 0) {                         // B frags reused across both M-half phases
#pragma unroll
        for (int nt = 0; nt < 4; ++nt) {
          const int row = wn * 64 + nt * 16 + c16;
          bf[nt] = *(const short8*)(Bbuf + row * 64 + (((ks * 4 + quad) ^ h7) * 8));
        }
      }
      __builtin_amdgcn_s_barrier();
      asm volatile("s_waitcnt lgkmcnt(0)" ::: "memory");
      __builtin_amdgcn_sched_barrier(0);     // rule 18: keep MFMA below the wait
      __builtin_amdgcn_s_setprio(1);
#pragma unroll
      for (int i = 0; i < 4; ++i)
#pragma unroll
        for (int nt = 0; nt < 4; ++nt)
          acc[hh * 4 + i][nt] =
              __builtin_amdgcn_mfma_f32_16x16x32_bf16(af[i], bf[nt], acc[hh * 4 + i][nt], 0, 0, 0);
      __builtin_amdgcn_s_setprio(0);
      __builtin_amdgcn_s_barrier();
    }
    // buffer cur is fully consumed (all waves past the last lgkmcnt+barrier) — refill.
    if (kt + 2 < NT) stage(cur, kbeg + (kt + 2) * 64);
  }

  // ---------------- epilogues ----------------
  if (MODE == 1) {
    u16t* P = (mat == 0) ? P0 : (mat == 1) ? P1 : (mat == 2) ? P2 : P3;
#pragma unroll
    for (int mt = 0; mt < 8; ++mt) {
#pragma unroll
      for (int r = 0; r < 4; ++r) {
        const int row = m0 + wm * 128 + mt * 16 + quad * 4 + r;
        const size_t base = (size_t)row * DM;
#pragma unroll
        for (int nt = 0; nt < 4; ++nt) {
          const int col = n0 + wn * 64 + nt * 16 + c16;
          P[base + col] = f2bf(acc[mt][nt][r]);
        }
      }
    }
    return;
  }
  if (mat == 2) {   // Vt: transposed store
#pragma unroll
    for (int mt = 0; mt < 8; ++mt) {
#pragma unroll
      for (int r = 0; r < 4; ++r) {
        const int row = m0 + wm * 128 + mt * 16 + quad * 4 + r;
#pragma unroll
        for (int nt = 0; nt < 4; ++nt) {
          const int col = n0 + wn * 64 + nt * 16 + c16;
          Cv[(size_t)col * TS + row] = f2bf(acc[mt][nt][r]);
        }
      }
    }
    return;
  }
  // Q/K with fused RoPE (pairs are (nt, nt+1) thanks to the weight permutation)
  u16t* C = mat ? Ck : Cq;
#pragma unroll
  for (int mt = 0; mt < 8; ++mt) {
#pragma unroll
    for (int r = 0; r < 4; ++r) {
      const int row = m0 + wm * 128 + mt * 16 + quad * 4 + r;   // = token t
      const size_t base = (size_t)row * DM;
#pragma unroll
      for (int ntp = 0; ntp < 4; ntp += 2) {
        const int col = n0 + wn * 64 + ntp * 16 + c16;
        const int p = col & 127;                  // position within head, bit4 == 0
        const int dorig = ((p >> 5) << 4) + c16;  // original d in [0,64)
        const float cv = cosb[row * DH + dorig];
        const float sv = sinb[row * DH + dorig];
        const float x1 = acc[mt][ntp][r];
        const float x2 = acc[mt][ntp + 1][r];
        C[base + col]      = f2bf(x1 * cv - x2 * sv);
        C[base + col + 16] = f2bf(x2 * cv + x1 * sv);
      }
    }
  }
}

// ---------------- combine: out = x + mask_row * (P0+P1+P2+P3), bf16 partials ------------
__global__ __launch_bounds__(256) void combine4_kernel(const u16t* __restrict__ P0,
                                                       const u16t* __restrict__ P1,
                                                       const u16t* __restrict__ P2,
                                                       const u16t* __restrict__ P3,
                                                       const float* __restrict__ x,
                                                       const int* __restrict__ am,
                                                       float* __restrict__ out) {
  const size_t idx = ((size_t)blockIdx.x * 256 + threadIdx.x) * 4;
  const int row = (int)(idx >> 11);           // idx / DM
  const float mk = (am[row] != 0) ? 1.f : 0.f;
  const u16x4 a = *(const u16x4*)(P0 + idx);
  const u16x4 b = *(const u16x4*)(P1 + idx);
  const u16x4 c = *(const u16x4*)(P2 + idx);
  const u16x4 d = *(const u16x4*)(P3 + idx);
  const f32x4 xr = *(const f32x4*)(x + idx);
  f32x4 o;
#pragma unroll
  for (int i = 0; i < 4; ++i)
    o[i] = xr[i] + mk * ((bf2f(a[i]) + bf2f(b[i])) + (bf2f(c[i]) + bf2f(d[i])));
  *(f32x4*)(out + idx) = o;
}

// ---------------- Flash attention (causal), LDS-staged K/V, 128-key tiles ----------------
__global__ __launch_bounds__(256) void attn_kernel(const u16t* __restrict__ Q,
                                                   const u16t* __restrict__ K,
                                                   const u16t* __restrict__ Vt,
                                                   const int* __restrict__ am,
                                                   u16t* __restrict__ O) {
  __shared__ u16t Klds[128 * 128];   // [key][d], swizzled granules, 32 KB
  __shared__ u16t Vlds[128 * 128];   // [d][key], swizzled granules, 32 KB
  __shared__ u16t Plds[4][2048];     // per-wave P: 4 chunks of 16x32, 16 KB
  const int wave = threadIdx.x >> 6;
  const int lane = threadIdx.x & 63;
  const int x    = blockIdx.x;
  const int half = x >> 8;                  // 0: qt 31..16, 1: qt 0..15
  const int idx  = x & 255;
  const int head = idx & (NH - 1);
  const int grp  = idx >> 4;                // 0..15
  const int qt   = half ? grp : (TS / 64 - 1 - grp);
  const int q0   = qt * 64 + wave * 16;
  const int quad = lane >> 4;
  const int c16  = lane & 15;
  const u16t* Qh  = Q + head * DH;
  const u16t* Kh  = K + head * DH;
  const u16t* Vth = Vt + (size_t)head * DH * TS;
  u16t* Pw = Plds[wave];

  const int row_s = (lane >> 4);    // 0..3 row within chunk
  const int g_s   = (lane & 15);    // granule slot

  short8 qf[4];
#pragma unroll
  for (int dc = 0; dc < 4; ++dc)
    qf[dc] = *(const short8*)(Qh + (size_t)(q0 + c16) * DM + dc * 32 + quad * 8);

  const f32x4 fzero = {0.f, 0.f, 0.f, 0.f};
  float m_run[4], l_run[4];
  f32x4 o_acc[8];
#pragma unroll
  for (int r = 0; r < 4; ++r) { m_run[r] = -1e30f; l_run[r] = 0.f; }
#pragma unroll
  for (int nt = 0; nt < 8; ++nt) o_acc[nt] = fzero;

  const float scale = 0.08838834764831845f;  // 1/sqrt(128)
  const int ntiles = (qt * 64 + 191) >> 7;   // 128-wide tiles covering keys 0..q0+63

  for (int kt = 0; kt < ntiles; ++kt) {
    const int k0 = kt * 128;
    __syncthreads();
#pragma unroll
    for (int c = 0; c < 8; ++c) {
      const int ch = wave * 8 + c;
      const int r  = 4 * ch + row_s;           // 0..127
      const int g  = g_s ^ (r & 15);
      async_copy16(Kh + (size_t)(k0 + r) * DM + g * 8, Klds + ch * 512);
      async_copy16(Vth + (size_t)r * TS + k0 + g * 8, Vlds + ch * 512);
    }
    __syncthreads();

    f32x4 s[8];
#pragma unroll
    for (int ns = 0; ns < 8; ++ns) {
      f32x4 sa = fzero;
      const int rr = ns * 16 + c16;
#pragma unroll
      for (int dc = 0; dc < 4; ++dc) {
        short8 kf = *(const short8*)(Klds + rr * 128 + (((dc * 4 + quad) ^ c16) * 8));
        sa = __builtin_amdgcn_mfma_f32_16x16x32_bf16(qf[dc], kf, sa, 0, 0, 0);
      }
      s[ns] = sa;
    }

    float pv[8][4], tmax[4];
#pragma unroll
    for (int r = 0; r < 4; ++r) tmax[r] = -1e30f;
#pragma unroll
    for (int ns = 0; ns < 8; ++ns) {
      const int key = k0 + ns * 16 + c16;
      const bool kok = (am[key] != 0);
#pragma unroll
      for (int r = 0; r < 4; ++r) {
        const int qrow = q0 + quad * 4 + r;
        float v = s[ns][r] * scale;
        if (key > qrow || !kok) v = -1e30f;
        pv[ns][r] = v;
        tmax[r] = fmaxf(tmax[r], v);
      }
    }
    float alpha[4], rsum[4];
#pragma unroll
    for (int r = 0; r < 4; ++r) {
      const float mn = fmaxf(m_run[r], row16_max(tmax[r]));
      alpha[r] = __expf(m_run[r] - mn);
      m_run[r] = mn;
      float rs = 0.f;
#pragma unroll
      for (int ns = 0; ns < 8; ++ns) {
        const float e = __expf(pv[ns][r] - mn);
        pv[ns][r] = e;
        rs += e;
      }
      rsum[r] = row16_sum(rs);
      l_run[r] = l_run[r] * alpha[r] + rsum[r];
    }

#pragma unroll
    for (int ns = 0; ns < 8; ++ns)
#pragma unroll
      for (int r = 0; r < 4; ++r)
        Pw[(ns >> 1) * 512 + (quad * 4 + r) * 32 + (ns & 1) * 16 + c16] = f2bf(pv[ns][r]);
    asm volatile("s_waitcnt lgkmcnt(0)" ::: "memory");
    short8 pf[4];
#pragma unroll
    for (int c = 0; c < 4; ++c)
      pf[c] = *(const short8*)(Pw + c * 512 + c16 * 32 + quad * 8);

#pragma unroll
    for (int nt = 0; nt < 8; ++nt)
#pragma unroll
      for (int r = 0; r < 4; ++r) o_acc[nt][r] *= alpha[r];
#pragma unroll
    for (int nt = 0; nt < 8; ++nt) {
      const int rr = nt * 16 + c16;
#pragma unroll
      for (int c = 0; c < 4; ++c) {
        short8 vf = *(const short8*)(Vlds + rr * 128 + (((c * 4 + quad) ^ c16) * 8));
        o_acc[nt] = __builtin_amdgcn_mfma_f32_16x16x32_bf16(pf[c], vf, o_acc[nt], 0, 0, 0);
      }
    }
  }

#pragma unroll
  for (int r = 0; r < 4; ++r) {
    const float inv = 1.0f / fmaxf(l_run[r], 1e-20f);
    const int qrow = q0 + quad * 4 + r;
#pragma unroll
    for (int nt = 0; nt < 8; ++nt)
      O[(size_t)qrow * DM + head * DH + nt * 16 + c16] = f2bf(o_acc[nt][r] * inv);
  }
}

extern "C" void kernel_launch(void* const* d_in, const int* in_sizes, int n_in,
                              void* d_out, int out_size, void* d_ws, size_t ws_size,
                              hipStream_t stream) {
  const float* x    = (const float*)d_in[0];
  const float* cosb = (const float*)d_in[1];
  const float* sinb = (const float*)d_in[2];
  const int*   am   = (const int*)d_in[3];
  const float* lnw  = (const float*)d_in[4];
  const float* Wq   = (const float*)d_in[5];
  const float* Wk   = (const float*)d_in[6];
  const float* Wv   = (const float*)d_in[7];
  const float* Wo   = (const float*)d_in[8];
  float* out = (float*)d_out;

  u16t* h    = (u16t*)d_ws;                 // (T, D) bf16   [0, 8 MB)   ; out-proj P0
  u16t* Q    = h + (size_t)TS * DM;         //               [8, 16)     ; out-proj P1
  u16t* K    = Q + (size_t)TS * DM;         //               [16, 24)    ; out-proj P2
  u16t* Vt   = K + (size_t)TS * DM;         //               [24, 32)    ; out-proj P3
  u16t* attn = Vt + (size_t)TS * DM;        //               [32, 40)
  u16t* Wb   = attn + (size_t)TS * DM;      // 4 x (D, D)    [40, 72)
  u16t* Wqb = Wb;
  u16t* Wkb = Wb + (size_t)DM * DM;
  u16t* Wvb = Wb + 2 * (size_t)DM * DM;
  u16t* Wob = Wb + 3 * (size_t)DM * DM;

  cast_rms_kernel<<<16384 + TS, 256, 0, stream>>>(Wq, Wk, Wv, Wo, Wb, x, lnw, h);
  // QKV: 8x8 tiles x 3 mats = 192 blocks of 512 threads, 8-phase schedule
  gemm8<0><<<192, 512, 0, stream>>>(h, Wqb, Wkb, Wvb, Q, K, Vt,
                                    nullptr, nullptr, nullptr, nullptr, cosb, sinb);
  attn_kernel<<<NH * (TS / 64), 256, 0, stream>>>(Q, K, Vt, am, attn);
  // out-proj: 64 tiles x split-K=4 = 256 blocks; bf16 partials into dead h/Q/K/Vt
  gemm8<1><<<256, 512, 0, stream>>>(attn, Wob, nullptr, nullptr,
                                    nullptr, nullptr, nullptr,
                                    h, Q, K, Vt, nullptr, nullptr);
  combine4_kernel<<<(TS * DM / 4) / 256, 256, 0, stream>>>(h, Q, K, Vt, x, am, out);
}

// Round 5
// 292.219 us; speedup vs baseline: 1.0617x; 1.0261x over previous
//
#include <hip/hip_runtime.h>
#include <stdint.h>

#define TS 2048
#define DM 2048
#define NH 16
#define DH 128

typedef unsigned short u16t;
typedef __attribute__((ext_vector_type(8))) short short8;
typedef __attribute__((ext_vector_type(4))) float f32x4;
typedef __attribute__((ext_vector_type(4))) unsigned int u32x4;
typedef __attribute__((ext_vector_type(4))) unsigned short u16x4;

__device__ __forceinline__ float bf2f(u16t b) {
  return __uint_as_float(((unsigned int)b) << 16);
}
__device__ __forceinline__ u16t f2bf(float f) {
  unsigned int u = __float_as_uint(f);
  u += 0x7FFFu + ((u >> 16) & 1u);   // round-to-nearest-even
  return (u16t)(u >> 16);
}

// async global->LDS, 16B per lane. LDS dest = wave-uniform base + lane*16.
__device__ __forceinline__ void async_copy16(const u16t* g, u16t* l) {
  __builtin_amdgcn_global_load_lds((const __attribute__((address_space(1))) void*)g,
                                   (__attribute__((address_space(3))) void*)l, 16, 0, 0);
}

// DPP row_ror within 16-lane rows: pure-VALU cross-lane (vs ds_bpermute for __shfl).
#define DPP_ROR_F(x, n) __uint_as_float(__builtin_amdgcn_update_dpp( \
    0, (int)__float_as_uint(x), 0x120 | (n), 0xF, 0xF, true))

__device__ __forceinline__ float row16_max(float x) {
  x = fmaxf(x, DPP_ROR_F(x, 8));
  x = fmaxf(x, DPP_ROR_F(x, 4));
  x = fmaxf(x, DPP_ROR_F(x, 2));
  x = fmaxf(x, DPP_ROR_F(x, 1));
  return x;
}
__device__ __forceinline__ float row16_sum(float x) {
  x += DPP_ROR_F(x, 8);
  x += DPP_ROR_F(x, 4);
  x += DPP_ROR_F(x, 2);
  x += DPP_ROR_F(x, 1);
  return x;
}

// ---------------- fused: fp32->bf16 weight cast (blocks 0..16383) + RMSNorm (rest) ----
// Wq/Wk rows are PERMUTED within each head at cast time so that RoPE partners
// (d, d+64) land at columns (p, p+16): p = (d>>4)*32 + (d&15) [+16 for d>=64].
// In the GEMM C-fragment, col and col+16 are the same lane / adjacent nt register,
// so RoPE becomes a pure in-register epilogue op. Q.K dot is invariant (same perm).
__global__ __launch_bounds__(256) void cast_rms_kernel(const float* __restrict__ W0,
                                                       const float* __restrict__ W1,
                                                       const float* __restrict__ W2,
                                                       const float* __restrict__ W3,
                                                       u16t* __restrict__ outw,
                                                       const float* __restrict__ x,
                                                       const float* __restrict__ lnw,
                                                       u16t* __restrict__ h) {
  if (blockIdx.x < 16384) {
    const int idx = blockIdx.x * 256 + threadIdx.x;   // 4M threads, 4 elems each
    const int mat = idx >> 20;
    const size_t off = (size_t)(idx & 0xFFFFF) * 4;
    const float* W = (mat == 0) ? W0 : (mat == 1) ? W1 : (mat == 2) ? W2 : W3;
    const f32x4 v = *(const f32x4*)(W + off);
    size_t dstoff = off;
    if (mat < 2) {   // permute output-feature rows of Wq, Wk
      const int row = (int)(off >> 11);
      const int col = (int)(off & 2047);
      const int d = row & 127;
      const int e = d & 63;
      const int p = ((e >> 4) * 32 + (e & 15)) + ((d >> 6) << 4);
      dstoff = ((size_t)((row & ~127) | p) << 11) | (size_t)col;
    }
    union { u16t s[4]; uint64_t u; } o;
#pragma unroll
    for (int i = 0; i < 4; ++i) o.s[i] = f2bf(v[i]);
    *(uint64_t*)(outw + (size_t)mat * (DM * DM) + dstoff) = o.u;
    return;
  }
  const int row = blockIdx.x - 16384;
  const int tid = threadIdx.x;
  const float* xr = x + (size_t)row * DM + tid * 8;
  f32x4 v0 = *(const f32x4*)(xr);
  f32x4 v1 = *(const f32x4*)(xr + 4);
  float f[8];
#pragma unroll
  for (int i = 0; i < 4; ++i) { f[i] = v0[i]; f[i + 4] = v1[i]; }
  float ss = 0.f;
#pragma unroll
  for (int i = 0; i < 8; ++i) ss += f[i] * f[i];
#pragma unroll
  for (int off = 1; off < 64; off <<= 1) ss += __shfl_xor(ss, off, 64);
  __shared__ float wsum[4];
  if ((tid & 63) == 0) wsum[tid >> 6] = ss;
  __syncthreads();
  float tot = wsum[0] + wsum[1] + wsum[2] + wsum[3];
  float rs = rsqrtf(tot * (1.0f / DM) + 1e-5f);
  f32x4 w0 = *(const f32x4*)(lnw + tid * 8);
  f32x4 w1 = *(const f32x4*)(lnw + tid * 8 + 4);
  u32x4 o;
#pragma unroll
  for (int i = 0; i < 4; ++i) {
    unsigned int lo = f2bf(f[2 * i]     * ((2 * i     < 4) ? w0[2 * i]     : w1[2 * i - 4]) * rs);
    unsigned int hi = f2bf(f[2 * i + 1] * ((2 * i + 1 < 4) ? w0[2 * i + 1] : w1[2 * i - 3]) * rs);
    o[i] = lo | (hi << 16);
  }
  *(u32x4*)(h + (size_t)row * DM + tid * 8) = o;
}

// ---------------- 256x256 2-phase GEMM C = A * B^T (bf16, K contiguous) ----------------
// Round-4 post-mortem: the 8-phase schedule (9 barriers/K-tile) was sync-bound at this
// shape (MfmaUtil 23%, 1 block/CU, 32 K-tiles). This is the catalog T3-MINIMUM loop:
// per K-tile {stage(kt+1) issued early; ds_read all frags; 64-MFMA cluster with
// compiler-scheduled waits; vmcnt(0); barrier} -> ONE barrier + one vmcnt per K-tile.
// vmcnt(0) is cheap: the stage had the whole ~2.5k-cycle compute phase to land.
// LDS swizzle kept (proven 0-conflict): LDS slot (r,j) holds global granule j^(r&7)
// via pre-swizzled global source (linear LDS dest); read XORs with row&7.
// MODE 0: 8m x 8n x 3 mats. mat 0/1 -> Q/K fused in-register RoPE (weights
//         pre-permuted); mat 2 -> Vt transposed store.
// MODE 1: out-proj split-K=4 (mat = wgid>>6), bf16 partial store to P0..P3.
template <int MODE>
__global__ __launch_bounds__(512, 2) void gemm8(
    const u16t* __restrict__ A,
    const u16t* __restrict__ B0, const u16t* __restrict__ B1, const u16t* __restrict__ B2,
    u16t* __restrict__ Cq, u16t* __restrict__ Ck, u16t* __restrict__ Cv,
    u16t* __restrict__ P0, u16t* __restrict__ P1,
    u16t* __restrict__ P2, u16t* __restrict__ P3,
    const float* __restrict__ cosb, const float* __restrict__ sinb) {
  __shared__ u16t Ab[2][256 * 64];   // 64 KB (2 x 32 KB)
  __shared__ u16t Bb[2][256 * 64];   // 64 KB
  const int tid  = threadIdx.x;
  const int wave = tid >> 6;
  const int lane = tid & 63;
  const int quad = lane >> 4;
  const int c16  = lane & 15;
  const int h7   = c16 & 7;
  const int wm   = wave >> 2;        // 0..1  (M half)
  const int wn   = wave & 3;         // 0..3  (N quarter)
  // XCD-aware swizzle (grid % 8 == 0 in both modes -> bijective)
  const int nwg  = gridDim.x;
  const int bid  = blockIdx.x;
  const int wgid = (bid & 7) * (nwg >> 3) + (bid >> 3);
  const int mat  = wgid >> 6;        // MODE0: matrix 0..2, MODE1: K-slice 0..3
  const int rem  = wgid & 63;
  const int m0   = (rem & 7) * 256;
  const int n0   = ((rem >> 3) & 7) * 256;
  const u16t* B  = (MODE == 0) ? (mat == 0 ? B0 : (mat == 1 ? B1 : B2)) : B0;
  const int kbeg = (MODE == 0) ? 0 : mat * (DM / 4);
  const int NT   = (MODE == 0) ? (DM / 64) : (DM / 4 / 64);   // 32 or 8 K-tiles

  // staging: per wave 8 x global_load_lds per K-tile (4 A-chunks + 4 B-chunks,
  // chunk = 8 rows x 128B = 1KB). lane -> row srow, granule (lane&7)^srow so that
  // LDS[r][j] holds global granule j^(r&7)  (involution; read applies same XOR).
  const int srow = lane >> 3;               // 0..7
  const int sg   = (lane & 7) ^ srow;       // permuted 16B granule
  auto stage = [&](int d, int k0) {
    const size_t koff = (size_t)k0 + sg * 8;
#pragma unroll
    for (int c = 0; c < 4; ++c) {
      const int rb = wave * 32 + c * 8;     // chunk row base (multiple of 8)
      async_copy16(A + (size_t)(m0 + rb + srow) * DM + koff, &Ab[d][rb * 64]);
      async_copy16(B + (size_t)(n0 + rb + srow) * DM + koff, &Bb[d][rb * 64]);
    }
  };

  const f32x4 fzero = {0.f, 0.f, 0.f, 0.f};
  f32x4 acc[8][4];
#pragma unroll
  for (int i = 0; i < 8; ++i)
#pragma unroll
    for (int j = 0; j < 4; ++j) acc[i][j] = fzero;

  // prologue: stage tile 0, wait, sync
  stage(0, kbeg);
  asm volatile("s_waitcnt vmcnt(0)" ::: "memory");
  __builtin_amdgcn_s_barrier();

  for (int kt = 0; kt < NT; ++kt) {
    const int cur = kt & 1;
    // issue next tile's loads FIRST so HBM latency hides under this tile's compute
    if (kt + 1 < NT) stage(cur ^ 1, kbeg + (kt + 1) * 64);
    const u16t* Abuf = Ab[cur];
    const u16t* Bbuf = Bb[cur];
    __builtin_amdgcn_s_setprio(1);
#pragma unroll
    for (int ks = 0; ks < 2; ++ks) {       // two K=32 halves; regs reused across ks
      short8 af[8], bfr[4];
#pragma unroll
      for (int i = 0; i < 8; ++i) {
        const int row = wm * 128 + i * 16 + c16;
        af[i] = *(const short8*)(Abuf + row * 64 + (((ks * 4 + quad) ^ h7) * 8));
      }
#pragma unroll
      for (int nt = 0; nt < 4; ++nt) {
        const int row = wn * 64 + nt * 16 + c16;
        bfr[nt] = *(const short8*)(Bbuf + row * 64 + (((ks * 4 + quad) ^ h7) * 8));
      }
#pragma unroll
      for (int i = 0; i < 8; ++i)
#pragma unroll
        for (int nt = 0; nt < 4; ++nt)
          acc[i][nt] =
              __builtin_amdgcn_mfma_f32_16x16x32_bf16(af[i], bfr[nt], acc[i][nt], 0, 0, 0);
    }
    __builtin_amdgcn_s_setprio(0);
    // next tile landed (had the whole compute phase) + all waves done reading cur
    asm volatile("s_waitcnt vmcnt(0)" ::: "memory");
    __builtin_amdgcn_s_barrier();
  }

  // ---------------- epilogues ----------------
  if (MODE == 1) {
    u16t* P = (mat == 0) ? P0 : (mat == 1) ? P1 : (mat == 2) ? P2 : P3;
#pragma unroll
    for (int mt = 0; mt < 8; ++mt) {
#pragma unroll
      for (int r = 0; r < 4; ++r) {
        const int row = m0 + wm * 128 + mt * 16 + quad * 4 + r;
        const size_t base = (size_t)row * DM;
#pragma unroll
        for (int nt = 0; nt < 4; ++nt) {
          const int col = n0 + wn * 64 + nt * 16 + c16;
          P[base + col] = f2bf(acc[mt][nt][r]);
        }
      }
    }
    return;
  }
  if (mat == 2) {   // Vt: transposed store
#pragma unroll
    for (int mt = 0; mt < 8; ++mt) {
#pragma unroll
      for (int r = 0; r < 4; ++r) {
        const int row = m0 + wm * 128 + mt * 16 + quad * 4 + r;
#pragma unroll
        for (int nt = 0; nt < 4; ++nt) {
          const int col = n0 + wn * 64 + nt * 16 + c16;
          Cv[(size_t)col * TS + row] = f2bf(acc[mt][nt][r]);
        }
      }
    }
    return;
  }
  // Q/K with fused RoPE (pairs are (nt, nt+1) thanks to the weight permutation)
  u16t* C = mat ? Ck : Cq;
#pragma unroll
  for (int mt = 0; mt < 8; ++mt) {
#pragma unroll
    for (int r = 0; r < 4; ++r) {
      const int row = m0 + wm * 128 + mt * 16 + quad * 4 + r;   // = token t
      const size_t base = (size_t)row * DM;
#pragma unroll
      for (int ntp = 0; ntp < 4; ntp += 2) {
        const int col = n0 + wn * 64 + ntp * 16 + c16;
        const int p = col & 127;                  // position within head, bit4 == 0
        const int dorig = ((p >> 5) << 4) + c16;  // original d in [0,64)
        const float cv = cosb[row * DH + dorig];
        const float sv = sinb[row * DH + dorig];
        const float x1 = acc[mt][ntp][r];
        const float x2 = acc[mt][ntp + 1][r];
        C[base + col]      = f2bf(x1 * cv - x2 * sv);
        C[base + col + 16] = f2bf(x2 * cv + x1 * sv);
      }
    }
  }
}

// ---------------- combine: out = x + mask_row * (P0+P1+P2+P3), bf16 partials ------------
__global__ __launch_bounds__(256) void combine4_kernel(const u16t* __restrict__ P0,
                                                       const u16t* __restrict__ P1,
                                                       const u16t* __restrict__ P2,
                                                       const u16t* __restrict__ P3,
                                                       const float* __restrict__ x,
                                                       const int* __restrict__ am,
                                                       float* __restrict__ out) {
  const size_t idx = ((size_t)blockIdx.x * 256 + threadIdx.x) * 4;
  const int row = (int)(idx >> 11);           // idx / DM
  const float mk = (am[row] != 0) ? 1.f : 0.f;
  const u16x4 a = *(const u16x4*)(P0 + idx);
  const u16x4 b = *(const u16x4*)(P1 + idx);
  const u16x4 c = *(const u16x4*)(P2 + idx);
  const u16x4 d = *(const u16x4*)(P3 + idx);
  const f32x4 xr = *(const f32x4*)(x + idx);
  f32x4 o;
#pragma unroll
  for (int i = 0; i < 4; ++i)
    o[i] = xr[i] + mk * ((bf2f(a[i]) + bf2f(b[i])) + (bf2f(c[i]) + bf2f(d[i])));
  *(f32x4*)(out + idx) = o;
}

// ---------------- Flash attention (causal), LDS-staged K/V, 128-key tiles ----------------
__global__ __launch_bounds__(256) void attn_kernel(const u16t* __restrict__ Q,
                                                   const u16t* __restrict__ K,
                                                   const u16t* __restrict__ Vt,
                                                   const int* __restrict__ am,
                                                   u16t* __restrict__ O) {
  __shared__ u16t Klds[128 * 128];   // [key][d], swizzled granules, 32 KB
  __shared__ u16t Vlds[128 * 128];   // [d][key], swizzled granules, 32 KB
  __shared__ u16t Plds[4][2048];     // per-wave P: 4 chunks of 16x32, 16 KB
  const int wave = threadIdx.x >> 6;
  const int lane = threadIdx.x & 63;
  const int x    = blockIdx.x;
  const int half = x >> 8;                  // 0: qt 31..16, 1: qt 0..15
  const int idx  = x & 255;
  const int head = idx & (NH - 1);
  const int grp  = idx >> 4;                // 0..15
  const int qt   = half ? grp : (TS / 64 - 1 - grp);
  const int q0   = qt * 64 + wave * 16;
  const int quad = lane >> 4;
  const int c16  = lane & 15;
  const u16t* Qh  = Q + head * DH;
  const u16t* Kh  = K + head * DH;
  const u16t* Vth = Vt + (size_t)head * DH * TS;
  u16t* Pw = Plds[wave];

  const int row_s = (lane >> 4);    // 0..3 row within chunk
  const int g_s   = (lane & 15);    // granule slot

  short8 qf[4];
#pragma unroll
  for (int dc = 0; dc < 4; ++dc)
    qf[dc] = *(const short8*)(Qh + (size_t)(q0 + c16) * DM + dc * 32 + quad * 8);

  const f32x4 fzero = {0.f, 0.f, 0.f, 0.f};
  float m_run[4], l_run[4];
  f32x4 o_acc[8];
#pragma unroll
  for (int r = 0; r < 4; ++r) { m_run[r] = -1e30f; l_run[r] = 0.f; }
#pragma unroll
  for (int nt = 0; nt < 8; ++nt) o_acc[nt] = fzero;

  const float scale = 0.08838834764831845f;  // 1/sqrt(128)
  const int ntiles = (qt * 64 + 191) >> 7;   // 128-wide tiles covering keys 0..q0+63

  for (int kt = 0; kt < ntiles; ++kt) {
    const int k0 = kt * 128;
    __syncthreads();
#pragma unroll
    for (int c = 0; c < 8; ++c) {
      const int ch = wave * 8 + c;
      const int r  = 4 * ch + row_s;           // 0..127
      const int g  = g_s ^ (r & 15);
      async_copy16(Kh + (size_t)(k0 + r) * DM + g * 8, Klds + ch * 512);
      async_copy16(Vth + (size_t)r * TS + k0 + g * 8, Vlds + ch * 512);
    }
    __syncthreads();

    f32x4 s[8];
#pragma unroll
    for (int ns = 0; ns < 8; ++ns) {
      f32x4 sa = fzero;
      const int rr = ns * 16 + c16;
#pragma unroll
      for (int dc = 0; dc < 4; ++dc) {
        short8 kf = *(const short8*)(Klds + rr * 128 + (((dc * 4 + quad) ^ c16) * 8));
        sa = __builtin_amdgcn_mfma_f32_16x16x32_bf16(qf[dc], kf, sa, 0, 0, 0);
      }
      s[ns] = sa;
    }

    float pv[8][4], tmax[4];
#pragma unroll
    for (int r = 0; r < 4; ++r) tmax[r] = -1e30f;
#pragma unroll
    for (int ns = 0; ns < 8; ++ns) {
      const int key = k0 + ns * 16 + c16;
      const bool kok = (am[key] != 0);
#pragma unroll
      for (int r = 0; r < 4; ++r) {
        const int qrow = q0 + quad * 4 + r;
        float v = s[ns][r] * scale;
        if (key > qrow || !kok) v = -1e30f;
        pv[ns][r] = v;
        tmax[r] = fmaxf(tmax[r], v);
      }
    }
    float alpha[4], rsum[4];
#pragma unroll
    for (int r = 0; r < 4; ++r) {
      const float mn = fmaxf(m_run[r], row16_max(tmax[r]));
      alpha[r] = __expf(m_run[r] - mn);
      m_run[r] = mn;
      float rs = 0.f;
#pragma unroll
      for (int ns = 0; ns < 8; ++ns) {
        const float e = __expf(pv[ns][r] - mn);
        pv[ns][r] = e;
        rs += e;
      }
      rsum[r] = row16_sum(rs);
      l_run[r] = l_run[r] * alpha[r] + rsum[r];
    }

#pragma unroll
    for (int ns = 0; ns < 8; ++ns)
#pragma unroll
      for (int r = 0; r < 4; ++r)
        Pw[(ns >> 1) * 512 + (quad * 4 + r) * 32 + (ns & 1) * 16 + c16] = f2bf(pv[ns][r]);
    asm volatile("s_waitcnt lgkmcnt(0)" ::: "memory");
    short8 pf[4];
#pragma unroll
    for (int c = 0; c < 4; ++c)
      pf[c] = *(const short8*)(Pw + c * 512 + c16 * 32 + quad * 8);

#pragma unroll
    for (int nt = 0; nt < 8; ++nt)
#pragma unroll
      for (int r = 0; r < 4; ++r) o_acc[nt][r] *= alpha[r];
#pragma unroll
    for (int nt = 0; nt < 8; ++nt) {
      const int rr = nt * 16 + c16;
#pragma unroll
      for (int c = 0; c < 4; ++c) {
        short8 vf = *(const short8*)(Vlds + rr * 128 + (((c * 4 + quad) ^ c16) * 8));
        o_acc[nt] = __builtin_amdgcn_mfma_f32_16x16x32_bf16(pf[c], vf, o_acc[nt], 0, 0, 0);
      }
    }
  }

#pragma unroll
  for (int r = 0; r < 4; ++r) {
    const float inv = 1.0f / fmaxf(l_run[r], 1e-20f);
    const int qrow = q0 + quad * 4 + r;
#pragma unroll
    for (int nt = 0; nt < 8; ++nt)
      O[(size_t)qrow * DM + head * DH + nt * 16 + c16] = f2bf(o_acc[nt][r] * inv);
  }
}

extern "C" void kernel_launch(void* const* d_in, const int* in_sizes, int n_in,
                              void* d_out, int out_size, void* d_ws, size_t ws_size,
                              hipStream_t stream) {
  const float* x    = (const float*)d_in[0];
  const float* cosb = (const float*)d_in[1];
  const float* sinb = (const float*)d_in[2];
  const int*   am   = (const int*)d_in[3];
  const float* lnw  = (const float*)d_in[4];
  const float* Wq   = (const float*)d_in[5];
  const float* Wk   = (const float*)d_in[6];
  const float* Wv   = (const float*)d_in[7];
  const float* Wo   = (const float*)d_in[8];
  float* out = (float*)d_out;

  u16t* h    = (u16t*)d_ws;                 // (T, D) bf16   [0, 8 MB)   ; out-proj P0
  u16t* Q    = h + (size_t)TS * DM;         //               [8, 16)     ; out-proj P1
  u16t* K    = Q + (size_t)TS * DM;         //               [16, 24)    ; out-proj P2
  u16t* Vt   = K + (size_t)TS * DM;         //               [24, 32)    ; out-proj P3
  u16t* attn = Vt + (size_t)TS * DM;        //               [32, 40)
  u16t* Wb   = attn + (size_t)TS * DM;      // 4 x (D, D)    [40, 72)
  u16t* Wqb = Wb;
  u16t* Wkb = Wb + (size_t)DM * DM;
  u16t* Wvb = Wb + 2 * (size_t)DM * DM;
  u16t* Wob = Wb + 3 * (size_t)DM * DM;

  cast_rms_kernel<<<16384 + TS, 256, 0, stream>>>(Wq, Wk, Wv, Wo, Wb, x, lnw, h);
  // QKV: 8x8 tiles x 3 mats = 192 blocks of 512 threads, 2-phase schedule
  gemm8<0><<<192, 512, 0, stream>>>(h, Wqb, Wkb, Wvb, Q, K, Vt,
                                    nullptr, nullptr, nullptr, nullptr, cosb, sinb);
  attn_kernel<<<NH * (TS / 64), 256, 0, stream>>>(Q, K, Vt, am, attn);
  // out-proj: 64 tiles x split-K=4 = 256 blocks; bf16 partials into dead h/Q/K/Vt
  gemm8<1><<<256, 512, 0, stream>>>(attn, Wob, nullptr, nullptr,
                                    nullptr, nullptr, nullptr,
                                    h, Q, K, Vt, nullptr, nullptr);
  combine4_kernel<<<(TS * DM / 4) / 256, 256, 0, stream>>>(h, Q, K, Vt, x, am, out);
}

// Round 9
// 281.335 us; speedup vs baseline: 1.1028x; 1.0387x over previous
//
#include <hip/hip_runtime.h>
#include <stdint.h>

#define TS 2048
#define DM 2048
#define NH 16
#define DH 128

typedef unsigned short u16t;
typedef __attribute__((ext_vector_type(8))) short short8;
typedef __attribute__((ext_vector_type(4))) float f32x4;
typedef __attribute__((ext_vector_type(4))) unsigned int u32x4;
typedef __attribute__((ext_vector_type(4))) unsigned short u16x4;

__device__ __forceinline__ float bf2f(u16t b) {
  return __uint_as_float(((unsigned int)b) << 16);
}
__device__ __forceinline__ u16t f2bf(float f) {
  unsigned int u = __float_as_uint(f);
  u += 0x7FFFu + ((u >> 16) & 1u);   // round-to-nearest-even
  return (u16t)(u >> 16);
}

// async global->LDS, 16B per lane. LDS dest = wave-uniform base + lane*16.
__device__ __forceinline__ void async_copy16(const u16t* g, u16t* l) {
  __builtin_amdgcn_global_load_lds((const __attribute__((address_space(1))) void*)g,
                                   (__attribute__((address_space(3))) void*)l, 16, 0, 0);
}

// DPP row_ror within 16-lane rows: pure-VALU cross-lane (vs ds_bpermute for __shfl).
#define DPP_ROR_F(x, n) __uint_as_float(__builtin_amdgcn_update_dpp( \
    0, (int)__float_as_uint(x), 0x120 | (n), 0xF, 0xF, true))

__device__ __forceinline__ float row16_max(float x) {
  x = fmaxf(x, DPP_ROR_F(x, 8));
  x = fmaxf(x, DPP_ROR_F(x, 4));
  x = fmaxf(x, DPP_ROR_F(x, 2));
  x = fmaxf(x, DPP_ROR_F(x, 1));
  return x;
}
__device__ __forceinline__ float row16_sum(float x) {
  x += DPP_ROR_F(x, 8);
  x += DPP_ROR_F(x, 4);
  x += DPP_ROR_F(x, 2);
  x += DPP_ROR_F(x, 1);
  return x;
}

// ---------------- fused: fp32->bf16 weight cast (blocks 0..16383) + RMSNorm (rest) ----
// Wq/Wk rows are PERMUTED within each head at cast time so that RoPE partners
// (d, d+64) land at columns (p, p+16): p = (d>>4)*32 + (d&15) [+16 for d>=64].
// In the GEMM C-fragment, col and col+16 are the same lane / adjacent nt register,
// so RoPE becomes a pure in-register epilogue op. Q.K dot is invariant (same perm).
__global__ __launch_bounds__(256) void cast_rms_kernel(const float* __restrict__ W0,
                                                       const float* __restrict__ W1,
                                                       const float* __restrict__ W2,
                                                       const float* __restrict__ W3,
                                                       u16t* __restrict__ outw,
                                                       const float* __restrict__ x,
                                                       const float* __restrict__ lnw,
                                                       u16t* __restrict__ h) {
  if (blockIdx.x < 16384) {
    const int idx = blockIdx.x * 256 + threadIdx.x;   // 4M threads, 4 elems each
    const int mat = idx >> 20;
    const size_t off = (size_t)(idx & 0xFFFFF) * 4;
    const float* W = (mat == 0) ? W0 : (mat == 1) ? W1 : (mat == 2) ? W2 : W3;
    const f32x4 v = *(const f32x4*)(W + off);
    size_t dstoff = off;
    if (mat < 2) {   // permute output-feature rows of Wq, Wk
      const int row = (int)(off >> 11);
      const int col = (int)(off & 2047);
      const int d = row & 127;
      const int e = d & 63;
      const int p = ((e >> 4) * 32 + (e & 15)) + ((d >> 6) << 4);
      dstoff = ((size_t)((row & ~127) | p) << 11) | (size_t)col;
    }
    union { u16t s[4]; uint64_t u; } o;
#pragma unroll
    for (int i = 0; i < 4; ++i) o.s[i] = f2bf(v[i]);
    *(uint64_t*)(outw + (size_t)mat * (DM * DM) + dstoff) = o.u;
    return;
  }
  const int row = blockIdx.x - 16384;
  const int tid = threadIdx.x;
  const float* xr = x + (size_t)row * DM + tid * 8;
  f32x4 v0 = *(const f32x4*)(xr);
  f32x4 v1 = *(const f32x4*)(xr + 4);
  float f[8];
#pragma unroll
  for (int i = 0; i < 4; ++i) { f[i] = v0[i]; f[i + 4] = v1[i]; }
  float ss = 0.f;
#pragma unroll
  for (int i = 0; i < 8; ++i) ss += f[i] * f[i];
#pragma unroll
  for (int off = 1; off < 64; off <<= 1) ss += __shfl_xor(ss, off, 64);
  __shared__ float wsum[4];
  if ((tid & 63) == 0) wsum[tid >> 6] = ss;
  __syncthreads();
  float tot = wsum[0] + wsum[1] + wsum[2] + wsum[3];
  float rs = rsqrtf(tot * (1.0f / DM) + 1e-5f);
  f32x4 w0 = *(const f32x4*)(lnw + tid * 8);
  f32x4 w1 = *(const f32x4*)(lnw + tid * 8 + 4);
  u32x4 o;
#pragma unroll
  for (int i = 0; i < 4; ++i) {
    unsigned int lo = f2bf(f[2 * i]     * ((2 * i     < 4) ? w0[2 * i]     : w1[2 * i - 4]) * rs);
    unsigned int hi = f2bf(f[2 * i + 1] * ((2 * i + 1 < 4) ? w0[2 * i + 1] : w1[2 * i - 3]) * rs);
    o[i] = lo | (hi << 16);
  }
  *(u32x4*)(h + (size_t)row * DM + tid * 8) = o;
}

// ---------------- fused QKV GEMM: one block computes Q,K,V for a 128x128 tile ----------
// Round-5 post-mortem: 256^2 single-mat blocks = 192 blocks (0.75/CU, 25% of CUs idle)
// and 3x duplicated A staging + A ds_reads. Fused tile: 128 tokens x 128 feats x 3 mats,
// BK=64, 8 waves (2M x 4N), LDS = A[2] 32KB + B[3][2] 96KB = 128 KiB, grid 16x16=256
// blocks = exactly 1/CU. Per K-tile: A staged ONCE for 3 mats (2A+6B gloads/wave),
// af fragments feed 3 B-sets -> 48 MFMA/wave/K-tile; per-tile sync amortized over 3x
// MFLOP. 2-phase schedule + granule swizzle (proven 0-conflict) kept from round 5.
// mat 0/1 -> Q/K fused in-register RoPE (weights pre-permuted); mat 2 -> Vt transposed.
__global__ __launch_bounds__(512, 2) void gemm_qkv(
    const u16t* __restrict__ A,
    const u16t* __restrict__ B0, const u16t* __restrict__ B1, const u16t* __restrict__ B2,
    u16t* __restrict__ Cq, u16t* __restrict__ Ck, u16t* __restrict__ Cv,
    const float* __restrict__ cosb, const float* __restrict__ sinb) {
  __shared__ u16t Ab[2][128 * 64];      // 32 KB
  __shared__ u16t Bb[3][2][128 * 64];   // 96 KB
  const int tid  = threadIdx.x;
  const int wave = tid >> 6;
  const int lane = tid & 63;
  const int quad = lane >> 4;
  const int c16  = lane & 15;
  const int h7   = c16 & 7;
  const int wm   = wave >> 2;        // 0..1  (token half: 64 rows)
  const int wn   = wave & 3;         // 0..3  (feature quarter: 32 cols)
  // XCD-aware swizzle, grid 256 -> 32 consecutive tiles per XCD (bijective)
  const int bid  = blockIdx.x;
  const int wgid = (bid & 7) * 32 + (bid >> 3);
  const int m0   = (wgid & 15) * 128;
  const int n0   = (wgid >> 4) * 128;

  // staging: chunk = 8 rows x 128B = 1KB. lane -> row srow, granule (lane&7)^srow so
  // LDS[r][j] holds global granule j^(r&7) (involution; read applies same XOR).
  const int srow = lane >> 3;               // 0..7
  const int sg   = (lane & 7) ^ srow;       // permuted 16B granule
  auto stage = [&](int d, int k0) {
    const size_t koff = (size_t)k0 + sg * 8;
#pragma unroll
    for (int c = 0; c < 2; ++c) {
      const int rb = wave * 16 + c * 8;     // chunk row base 0..127 (multiple of 8)
      async_copy16(A  + (size_t)(m0 + rb + srow) * DM + koff, &Ab[d][rb * 64]);
      async_copy16(B0 + (size_t)(n0 + rb + srow) * DM + koff, &Bb[0][d][rb * 64]);
      async_copy16(B1 + (size_t)(n0 + rb + srow) * DM + koff, &Bb[1][d][rb * 64]);
      async_copy16(B2 + (size_t)(n0 + rb + srow) * DM + koff, &Bb[2][d][rb * 64]);
    }
  };

  const f32x4 fzero = {0.f, 0.f, 0.f, 0.f};
  f32x4 acc[3][4][2];   // [mat][mt][nt] -> 96 VGPR
#pragma unroll
  for (int m = 0; m < 3; ++m)
#pragma unroll
    for (int i = 0; i < 4; ++i)
#pragma unroll
      for (int j = 0; j < 2; ++j) acc[m][i][j] = fzero;

  stage(0, 0);
  asm volatile("s_waitcnt vmcnt(0)" ::: "memory");
  __builtin_amdgcn_s_barrier();

  for (int kt = 0; kt < DM / 64; ++kt) {
    const int cur = kt & 1;
    if (kt + 1 < DM / 64) stage(cur ^ 1, (kt + 1) * 64);   // prefetch under compute
    const u16t* Abuf = Ab[cur];
    __builtin_amdgcn_s_setprio(1);
#pragma unroll
    for (int ks = 0; ks < 2; ++ks) {       // two K=32 halves
      const int gsw = ((ks * 4 + quad) ^ h7) * 8;
      short8 af[4], bfr[3][2];
#pragma unroll
      for (int i = 0; i < 4; ++i)
        af[i] = *(const short8*)(Abuf + (wm * 64 + i * 16 + c16) * 64 + gsw);
#pragma unroll
      for (int m = 0; m < 3; ++m)
#pragma unroll
        for (int nt = 0; nt < 2; ++nt)
          bfr[m][nt] = *(const short8*)(&Bb[m][cur][0] + (wn * 32 + nt * 16 + c16) * 64 + gsw);
#pragma unroll
      for (int m = 0; m < 3; ++m)
#pragma unroll
        for (int i = 0; i < 4; ++i)
#pragma unroll
          for (int nt = 0; nt < 2; ++nt)
            acc[m][i][nt] =
                __builtin_amdgcn_mfma_f32_16x16x32_bf16(af[i], bfr[m][nt], acc[m][i][nt], 0, 0, 0);
    }
    __builtin_amdgcn_s_setprio(0);
    asm volatile("s_waitcnt vmcnt(0)" ::: "memory");
    __builtin_amdgcn_s_barrier();
  }

  // ---------------- epilogues ----------------
  // Q/K with fused RoPE: each wave's cols are (p, p+16) pairs, p = wn*32 + c16
  // (bit4 of p always 0). Original d = ((p>>5)<<4) + (p&15).
#pragma unroll
  for (int mat = 0; mat < 2; ++mat) {
    u16t* C = mat ? Ck : Cq;
#pragma unroll
    for (int mt = 0; mt < 4; ++mt) {
#pragma unroll
      for (int r = 0; r < 4; ++r) {
        const int row = m0 + wm * 64 + mt * 16 + quad * 4 + r;   // = token t
        const size_t base = (size_t)row * DM;
        const int col = n0 + wn * 32 + c16;
        const int p = col & 127;
        const int dorig = ((p >> 5) << 4) + c16;
        const float cv = cosb[row * DH + dorig];
        const float sv = sinb[row * DH + dorig];
        const float x1 = acc[mat][mt][0][r];
        const float x2 = acc[mat][mt][1][r];
        C[base + col]      = f2bf(x1 * cv - x2 * sv);
        C[base + col + 16] = f2bf(x2 * cv + x1 * sv);
      }
    }
  }
  // V: transposed store
#pragma unroll
  for (int mt = 0; mt < 4; ++mt) {
#pragma unroll
    for (int r = 0; r < 4; ++r) {
      const int row = m0 + wm * 64 + mt * 16 + quad * 4 + r;
#pragma unroll
      for (int nt = 0; nt < 2; ++nt) {
        const int col = n0 + wn * 32 + nt * 16 + c16;
        Cv[(size_t)col * TS + row] = f2bf(acc[2][mt][nt][r]);
      }
    }
  }
}

// ---------------- out-proj GEMM: 256x256 tile, split-K=4, 2-phase (round-5 proven) ----
__global__ __launch_bounds__(512, 2) void gemm_out(
    const u16t* __restrict__ A, const u16t* __restrict__ B0,
    u16t* __restrict__ P0, u16t* __restrict__ P1,
    u16t* __restrict__ P2, u16t* __restrict__ P3) {
  __shared__ u16t Ab[2][256 * 64];   // 64 KB
  __shared__ u16t Bb[2][256 * 64];   // 64 KB
  const int tid  = threadIdx.x;
  const int wave = tid >> 6;
  const int lane = tid & 63;
  const int quad = lane >> 4;
  const int c16  = lane & 15;
  const int h7   = c16 & 7;
  const int wm   = wave >> 2;        // 0..1
  const int wn   = wave & 3;         // 0..3
  const int nwg  = gridDim.x;
  const int bid  = blockIdx.x;
  const int wgid = (bid & 7) * (nwg >> 3) + (bid >> 3);
  const int mat  = wgid >> 6;        // K-slice 0..3
  const int rem  = wgid & 63;
  const int m0   = (rem & 7) * 256;
  const int n0   = ((rem >> 3) & 7) * 256;
  const int kbeg = mat * (DM / 4);
  const int NT   = DM / 4 / 64;      // 8 K-tiles

  const int srow = lane >> 3;
  const int sg   = (lane & 7) ^ srow;
  auto stage = [&](int d, int k0) {
    const size_t koff = (size_t)k0 + sg * 8;
#pragma unroll
    for (int c = 0; c < 4; ++c) {
      const int rb = wave * 32 + c * 8;
      async_copy16(A + (size_t)(m0 + rb + srow) * DM + koff, &Ab[d][rb * 64]);
      async_copy16(B0 + (size_t)(n0 + rb + srow) * DM + koff, &Bb[d][rb * 64]);
    }
  };

  const f32x4 fzero = {0.f, 0.f, 0.f, 0.f};
  f32x4 acc[8][4];
#pragma unroll
  for (int i = 0; i < 8; ++i)
#pragma unroll
    for (int j = 0; j < 4; ++j) acc[i][j] = fzero;

  stage(0, kbeg);
  asm volatile("s_waitcnt vmcnt(0)" ::: "memory");
  __builtin_amdgcn_s_barrier();

  for (int kt = 0; kt < NT; ++kt) {
    const int cur = kt & 1;
    if (kt + 1 < NT) stage(cur ^ 1, kbeg + (kt + 1) * 64);
    const u16t* Abuf = Ab[cur];
    const u16t* Bbuf = Bb[cur];
    __builtin_amdgcn_s_setprio(1);
#pragma unroll
    for (int ks = 0; ks < 2; ++ks) {
      short8 af[8], bfr[4];
#pragma unroll
      for (int i = 0; i < 8; ++i) {
        const int row = wm * 128 + i * 16 + c16;
        af[i] = *(const short8*)(Abuf + row * 64 + (((ks * 4 + quad) ^ h7) * 8));
      }
#pragma unroll
      for (int nt = 0; nt < 4; ++nt) {
        const int row = wn * 64 + nt * 16 + c16;
        bfr[nt] = *(const short8*)(Bbuf + row * 64 + (((ks * 4 + quad) ^ h7) * 8));
      }
#pragma unroll
      for (int i = 0; i < 8; ++i)
#pragma unroll
        for (int nt = 0; nt < 4; ++nt)
          acc[i][nt] =
              __builtin_amdgcn_mfma_f32_16x16x32_bf16(af[i], bfr[nt], acc[i][nt], 0, 0, 0);
    }
    __builtin_amdgcn_s_setprio(0);
    asm volatile("s_waitcnt vmcnt(0)" ::: "memory");
    __builtin_amdgcn_s_barrier();
  }

  u16t* P = (mat == 0) ? P0 : (mat == 1) ? P1 : (mat == 2) ? P2 : P3;
#pragma unroll
  for (int mt = 0; mt < 8; ++mt) {
#pragma unroll
    for (int r = 0; r < 4; ++r) {
      const int row = m0 + wm * 128 + mt * 16 + quad * 4 + r;
      const size_t base = (size_t)row * DM;
#pragma unroll
      for (int nt = 0; nt < 4; ++nt) {
        const int col = n0 + wn * 64 + nt * 16 + c16;
        P[base + col] = f2bf(acc[mt][nt][r]);
      }
    }
  }
}

// ---------------- combine: out = x + mask_row * (P0+P1+P2+P3), bf16 partials ------------
__global__ __launch_bounds__(256) void combine4_kernel(const u16t* __restrict__ P0,
                                                       const u16t* __restrict__ P1,
                                                       const u16t* __restrict__ P2,
                                                       const u16t* __restrict__ P3,
                                                       const float* __restrict__ x,
                                                       const int* __restrict__ am,
                                                       float* __restrict__ out) {
  const size_t idx = ((size_t)blockIdx.x * 256 + threadIdx.x) * 4;
  const int row = (int)(idx >> 11);           // idx / DM
  const float mk = (am[row] != 0) ? 1.f : 0.f;
  const u16x4 a = *(const u16x4*)(P0 + idx);
  const u16x4 b = *(const u16x4*)(P1 + idx);
  const u16x4 c = *(const u16x4*)(P2 + idx);
  const u16x4 d = *(const u16x4*)(P3 + idx);
  const f32x4 xr = *(const f32x4*)(x + idx);
  f32x4 o;
#pragma unroll
  for (int i = 0; i < 4; ++i)
    o[i] = xr[i] + mk * ((bf2f(a[i]) + bf2f(b[i])) + (bf2f(c[i]) + bf2f(d[i])));
  *(f32x4*)(out + idx) = o;
}

// ---------------- Flash attention (causal), LDS-staged K/V, 128-key tiles ----------------
__global__ __launch_bounds__(256) void attn_kernel(const u16t* __restrict__ Q,
                                                   const u16t* __restrict__ K,
                                                   const u16t* __restrict__ Vt,
                                                   const int* __restrict__ am,
                                                   u16t* __restrict__ O) {
  __shared__ u16t Klds[128 * 128];   // [key][d], swizzled granules, 32 KB
  __shared__ u16t Vlds[128 * 128];   // [d][key], swizzled granules, 32 KB
  __shared__ u16t Plds[4][2048];     // per-wave P: 4 chunks of 16x32, 16 KB
  const int wave = threadIdx.x >> 6;
  const int lane = threadIdx.x & 63;
  const int x    = blockIdx.x;
  const int half = x >> 8;                  // 0: qt 31..16, 1: qt 0..15
  const int idx  = x & 255;
  const int head = idx & (NH - 1);
  const int grp  = idx >> 4;                // 0..15
  const int qt   = half ? grp : (TS / 64 - 1 - grp);
  const int q0   = qt * 64 + wave * 16;
  const int quad = lane >> 4;
  const int c16  = lane & 15;
  const u16t* Qh  = Q + head * DH;
  const u16t* Kh  = K + head * DH;
  const u16t* Vth = Vt + (size_t)head * DH * TS;
  u16t* Pw = Plds[wave];

  const int row_s = (lane >> 4);    // 0..3 row within chunk
  const int g_s   = (lane & 15);    // granule slot

  short8 qf[4];
#pragma unroll
  for (int dc = 0; dc < 4; ++dc)
    qf[dc] = *(const short8*)(Qh + (size_t)(q0 + c16) * DM + dc * 32 + quad * 8);

  const f32x4 fzero = {0.f, 0.f, 0.f, 0.f};
  float m_run[4], l_run[4];
  f32x4 o_acc[8];
#pragma unroll
  for (int r = 0; r < 4; ++r) { m_run[r] = -1e30f; l_run[r] = 0.f; }
#pragma unroll
  for (int nt = 0; nt < 8; ++nt) o_acc[nt] = fzero;

  const float scale = 0.08838834764831845f;  // 1/sqrt(128)
  const int ntiles = (qt * 64 + 191) >> 7;   // 128-wide tiles covering keys 0..q0+63

  for (int kt = 0; kt < ntiles; ++kt) {
    const int k0 = kt * 128;
    __syncthreads();
#pragma unroll
    for (int c = 0; c < 8; ++c) {
      const int ch = wave * 8 + c;
      const int r  = 4 * ch + row_s;           // 0..127
      const int g  = g_s ^ (r & 15);
      async_copy16(Kh + (size_t)(k0 + r) * DM + g * 8, Klds + ch * 512);
      async_copy16(Vth + (size_t)r * TS + k0 + g * 8, Vlds + ch * 512);
    }
    __syncthreads();

    f32x4 s[8];
#pragma unroll
    for (int ns = 0; ns < 8; ++ns) {
      f32x4 sa = fzero;
      const int rr = ns * 16 + c16;
#pragma unroll
      for (int dc = 0; dc < 4; ++dc) {
        short8 kf = *(const short8*)(Klds + rr * 128 + (((dc * 4 + quad) ^ c16) * 8));
        sa = __builtin_amdgcn_mfma_f32_16x16x32_bf16(qf[dc], kf, sa, 0, 0, 0);
      }
      s[ns] = sa;
    }

    float pv[8][4], tmax[4];
#pragma unroll
    for (int r = 0; r < 4; ++r) tmax[r] = -1e30f;
#pragma unroll
    for (int ns = 0; ns < 8; ++ns) {
      const int key = k0 + ns * 16 + c16;
      const bool kok = (am[key] != 0);
#pragma unroll
      for (int r = 0; r < 4; ++r) {
        const int qrow = q0 + quad * 4 + r;
        float v = s[ns][r] * scale;
        if (key > qrow || !kok) v = -1e30f;
        pv[ns][r] = v;
        tmax[r] = fmaxf(tmax[r], v);
      }
    }
    float alpha[4], rsum[4];
#pragma unroll
    for (int r = 0; r < 4; ++r) {
      const float mn = fmaxf(m_run[r], row16_max(tmax[r]));
      alpha[r] = __expf(m_run[r] - mn);
      m_run[r] = mn;
      float rs = 0.f;
#pragma unroll
      for (int ns = 0; ns < 8; ++ns) {
        const float e = __expf(pv[ns][r] - mn);
        pv[ns][r] = e;
        rs += e;
      }
      rsum[r] = row16_sum(rs);
      l_run[r] = l_run[r] * alpha[r] + rsum[r];
    }

#pragma unroll
    for (int ns = 0; ns < 8; ++ns)
#pragma unroll
      for (int r = 0; r < 4; ++r)
        Pw[(ns >> 1) * 512 + (quad * 4 + r) * 32 + (ns & 1) * 16 + c16] = f2bf(pv[ns][r]);
    asm volatile("s_waitcnt lgkmcnt(0)" ::: "memory");
    short8 pf[4];
#pragma unroll
    for (int c = 0; c < 4; ++c)
      pf[c] = *(const short8*)(Pw + c * 512 + c16 * 32 + quad * 8);

#pragma unroll
    for (int nt = 0; nt < 8; ++nt)
#pragma unroll
      for (int r = 0; r < 4; ++r) o_acc[nt][r] *= alpha[r];
#pragma unroll
    for (int nt = 0; nt < 8; ++nt) {
      const int rr = nt * 16 + c16;
#pragma unroll
      for (int c = 0; c < 4; ++c) {
        short8 vf = *(const short8*)(Vlds + rr * 128 + (((c * 4 + quad) ^ c16) * 8));
        o_acc[nt] = __builtin_amdgcn_mfma_f32_16x16x32_bf16(pf[c], vf, o_acc[nt], 0, 0, 0);
      }
    }
  }

#pragma unroll
  for (int r = 0; r < 4; ++r) {
    const float inv = 1.0f / fmaxf(l_run[r], 1e-20f);
    const int qrow = q0 + quad * 4 + r;
#pragma unroll
    for (int nt = 0; nt < 8; ++nt)
      O[(size_t)qrow * DM + head * DH + nt * 16 + c16] = f2bf(o_acc[nt][r] * inv);
  }
}

extern "C" void kernel_launch(void* const* d_in, const int* in_sizes, int n_in,
                              void* d_out, int out_size, void* d_ws, size_t ws_size,
                              hipStream_t stream) {
  const float* x    = (const float*)d_in[0];
  const float* cosb = (const float*)d_in[1];
  const float* sinb = (const float*)d_in[2];
  const int*   am   = (const int*)d_in[3];
  const float* lnw  = (const float*)d_in[4];
  const float* Wq   = (const float*)d_in[5];
  const float* Wk   = (const float*)d_in[6];
  const float* Wv   = (const float*)d_in[7];
  const float* Wo   = (const float*)d_in[8];
  float* out = (float*)d_out;

  u16t* h    = (u16t*)d_ws;                 // (T, D) bf16   [0, 8 MB)   ; out-proj P0
  u16t* Q    = h + (size_t)TS * DM;         //               [8, 16)     ; out-proj P1
  u16t* K    = Q + (size_t)TS * DM;         //               [16, 24)    ; out-proj P2
  u16t* Vt   = K + (size_t)TS * DM;         //               [24, 32)    ; out-proj P3
  u16t* attn = Vt + (size_t)TS * DM;        //               [32, 40)
  u16t* Wb   = attn + (size_t)TS * DM;      // 4 x (D, D)    [40, 72)
  u16t* Wqb = Wb;
  u16t* Wkb = Wb + (size_t)DM * DM;
  u16t* Wvb = Wb + 2 * (size_t)DM * DM;
  u16t* Wob = Wb + 3 * (size_t)DM * DM;

  cast_rms_kernel<<<16384 + TS, 256, 0, stream>>>(Wq, Wk, Wv, Wo, Wb, x, lnw, h);
  // fused QKV: 16x16 tiles = 256 blocks (1/CU), all 3 matrices per block
  gemm_qkv<<<256, 512, 0, stream>>>(h, Wqb, Wkb, Wvb, Q, K, Vt, cosb, sinb);
  attn_kernel<<<NH * (TS / 64), 256, 0, stream>>>(Q, K, Vt, am, attn);
  // out-proj: 64 tiles x split-K=4 = 256 blocks; bf16 partials into dead h/Q/K/Vt
  gemm_out<<<256, 512, 0, stream>>>(attn, Wob, h, Q, K, Vt);
  combine4_kernel<<<(TS * DM / 4) / 256, 256, 0, stream>>>(h, Q, K, Vt, x, am, out);
}